// Round 1
// baseline (36.358 us; speedup 1.0000x reference)
//
#include <hip/hip_runtime.h>

// Problem constants (fixed by setup_inputs / reference)
#define NPG    32768          // nodes per batch group
#define NTOT   131072         // B * NPG
#define WIN    256            // lookback window
#define MAXN   16             // max neighbors kept
#define RAD2   49             // RADIUS_PX^2, RADIUS_PX = int(0.01*640+1) = 7
#define DTMAX  10000          // int(0.01 * 1e6)

__global__ __launch_bounds__(256)
void tgn_edges_kernel(const float* __restrict__ pos, int* __restrict__ out) {
    __shared__ int2 sp[512];   // packed (x | y<<16, t) for nodes [b0-256, b0+256)

    const int tid = threadIdx.x;
    const int b0  = blockIdx.x * 256;

    // Stage + convert nodes [b0-256, b0+256) into LDS.
    #pragma unroll
    for (int s = 0; s < 2; ++s) {
        const int node = b0 - 256 + s * 256 + tid;
        int2 v = make_int2(0, 0);
        if (node >= 0) {
            const float x  = pos[3 * node + 0];
            const float y  = pos[3 * node + 1];
            const float tt = pos[3 * node + 2];
            // Must bit-match numpy float32: int32(denorm*pos + 0.001).
            // __fmul_rn/__fadd_rn prevent FMA contraction.
            const int px = (int)(__fadd_rn(__fmul_rn(640.0f,     x),  0.001f));
            const int py = (int)(__fadd_rn(__fmul_rn(480.0f,     y),  0.001f));
            const int pt = (int)(__fadd_rn(__fmul_rn(1000000.0f, tt), 0.001f));
            v.x = px | (py << 16);   // x in [0,640), y in [0,480) -> both fit 16 bits
            v.y = pt;
        }
        sp[s * 256 + tid] = v;
    }
    __syncthreads();

    const int  i  = b0 + tid;
    const int2 pi = sp[256 + tid];
    const int  ix = pi.x & 0xffff;
    const int  iy = pi.x >> 16;
    const int  it = pi.y;

    int count = 0;
    int* __restrict__ outsrc = out + (size_t)i * MAXN;
    int* __restrict__ outdst = out + (size_t)NTOT * MAXN + (size_t)i * MAXN;

    // A block needs the j>=0 / same-batch checks only if its window can
    // cross a batch boundary. b0 is a multiple of 256; batch boundaries are
    // multiples of 32768, so only (b0 & 32767)==0 blocks are "edge" blocks.
    const bool edge = (b0 & (NPG - 1)) == 0;

    if (!edge) {
        // Fast path: j>=0 and same-batch guaranteed; dt>=0 guaranteed
        // (t sorted ascending within batch; int conversion is monotonic).
        #pragma unroll 8
        for (int off = 1; off <= WIN; ++off) {
            const int2 pj = sp[256 + tid - off];
            const int dx = ix - (pj.x & 0xffff);
            const int dy = iy - (pj.x >> 16);
            const int d2 = dx * dx + dy * dy;
            const int dt = it - pj.y;
            const bool ok = (d2 <= RAD2) && (dt <= DTMAX);
            if (ok) {
                if (count < MAXN) {
                    outsrc[count] = i - off;   // src = j
                    outdst[count] = i;         // dst = i
                }
                ++count;
            }
        }
    } else {
        // Edge path: full condition set.
        #pragma unroll 4
        for (int off = 1; off <= WIN; ++off) {
            const int j = i - off;
            const int2 pj = sp[256 + tid - off];
            const int dx = ix - (pj.x & 0xffff);
            const int dy = iy - (pj.x >> 16);
            const int d2 = dx * dx + dy * dy;
            const int dt = it - pj.y;
            const bool ok = (j >= 0) && ((j >> 15) == (i >> 15)) &&
                            (d2 <= RAD2) && (dt >= 0) && (dt <= DTMAX);
            if (ok) {
                if (count < MAXN) {
                    outsrc[count] = j;
                    outdst[count] = i;
                }
                ++count;
            }
        }
    }
}

extern "C" void kernel_launch(void* const* d_in, const int* in_sizes, int n_in,
                              void* d_out, int out_size, void* d_ws, size_t ws_size,
                              hipStream_t stream) {
    const float* pos = (const float*)d_in[0];
    int* out = (int*)d_out;

    // Fill the whole output with -1 (0xFF bytes); the kernel then
    // scatter-writes only the (rare) real matches.
    hipMemsetAsync(d_out, 0xFF, (size_t)out_size * sizeof(int), stream);

    tgn_edges_kernel<<<NTOT / 256, 256, 0, stream>>>(pos, out);
}

// Round 2
// 35.365 us; speedup vs baseline: 1.0281x; 1.0281x over previous
//
#include <hip/hip_runtime.h>

// Problem constants (fixed by setup_inputs / reference)
#define NPG    32768          // nodes per batch group
#define NTOT   131072         // B * NPG
#define WIN    256            // lookback window
#define MAXN   16             // max neighbors kept
#define RAD2   49             // RADIUS_PX^2, RADIUS_PX = int(0.01*640+1) = 7
#define DTMAX  10000          // int(0.01 * 1e6)

__global__ __launch_bounds__(256)
void tgn_edges_kernel(const float* __restrict__ pos, int* __restrict__ out) {
    __shared__ int2 sp[512];   // packed (x | y<<16, t) for nodes [b0-256, b0+256)

    const int tid = threadIdx.x;
    const int b0  = blockIdx.x * 256;
    const int i   = b0 + tid;

    // ---- Fill this thread's 16+16 output slots with -1 (coalesced int4).
    // The scatter-writes below overwrite matches; same-thread same-address
    // ordering is guaranteed, so no extra fill dispatch is needed.
    int* __restrict__ outsrc = out + (size_t)i * MAXN;
    int* __restrict__ outdst = out + (size_t)NTOT * MAXN + (size_t)i * MAXN;
    {
        const int4 m1 = make_int4(-1, -1, -1, -1);
        int4* s4 = reinterpret_cast<int4*>(outsrc);
        int4* d4 = reinterpret_cast<int4*>(outdst);
        #pragma unroll
        for (int k = 0; k < 4; ++k) { s4[k] = m1; d4[k] = m1; }
    }

    // ---- Stage + convert nodes [b0-256, b0+256) into LDS.
    #pragma unroll
    for (int s = 0; s < 2; ++s) {
        const int node = b0 - 256 + s * 256 + tid;
        int2 v = make_int2(0, 0);
        if (node >= 0) {
            const float x  = pos[3 * node + 0];
            const float y  = pos[3 * node + 1];
            const float tt = pos[3 * node + 2];
            // Must bit-match numpy float32: int32(denorm*pos + 0.001).
            // __fmul_rn/__fadd_rn prevent FMA contraction.
            const int px = (int)(__fadd_rn(__fmul_rn(640.0f,     x),  0.001f));
            const int py = (int)(__fadd_rn(__fmul_rn(480.0f,     y),  0.001f));
            const int pt = (int)(__fadd_rn(__fmul_rn(1000000.0f, tt), 0.001f));
            v.x = px | (py << 16);   // x in [0,640), y in [0,480) -> both fit 16 bits
            v.y = pt;
        }
        sp[s * 256 + tid] = v;
    }
    __syncthreads();

    const int2 pi = sp[256 + tid];
    const int  ix = pi.x & 0xffff;
    const int  iy = pi.x >> 16;
    const int  it = pi.y;

    int count = 0;

    // A block needs the j>=0 / same-batch checks only if its window can
    // cross a batch boundary. b0 is a multiple of 256; batch boundaries are
    // multiples of 32768, so only (b0 & 32767)==0 blocks are "edge" blocks.
    const bool edge = (b0 & (NPG - 1)) == 0;

    if (!edge) {
        // Fast path: j>=0 and same-batch guaranteed; dt>=0 guaranteed
        // (t sorted ascending within batch; int conversion is monotonic).
        #pragma unroll 8
        for (int off = 1; off <= WIN; ++off) {
            const int2 pj = sp[256 + tid - off];
            const int dx = ix - (pj.x & 0xffff);
            const int dy = iy - (pj.x >> 16);
            const int d2 = dx * dx + dy * dy;
            const int dt = it - pj.y;
            const bool ok = (d2 <= RAD2) && (dt <= DTMAX);
            if (ok) {
                if (count < MAXN) {
                    outsrc[count] = i - off;   // src = j
                    outdst[count] = i;         // dst = i
                }
                ++count;
            }
        }
    } else {
        // Edge path: full condition set.
        #pragma unroll 4
        for (int off = 1; off <= WIN; ++off) {
            const int j = i - off;
            const int2 pj = sp[256 + tid - off];
            const int dx = ix - (pj.x & 0xffff);
            const int dy = iy - (pj.x >> 16);
            const int d2 = dx * dx + dy * dy;
            const int dt = it - pj.y;
            const bool ok = (j >= 0) && ((j >> 15) == (i >> 15)) &&
                            (d2 <= RAD2) && (dt >= 0) && (dt <= DTMAX);
            if (ok) {
                if (count < MAXN) {
                    outsrc[count] = j;
                    outdst[count] = i;
                }
                ++count;
            }
        }
    }
}

extern "C" void kernel_launch(void* const* d_in, const int* in_sizes, int n_in,
                              void* d_out, int out_size, void* d_ws, size_t ws_size,
                              hipStream_t stream) {
    const float* pos = (const float*)d_in[0];
    int* out = (int*)d_out;
    tgn_edges_kernel<<<NTOT / 256, 256, 0, stream>>>(pos, out);
}

// Round 3
// 31.653 us; speedup vs baseline: 1.1486x; 1.1173x over previous
//
#include <hip/hip_runtime.h>

// Problem constants (fixed by setup_inputs / reference)
#define NPG    32768          // nodes per batch group
#define NTOT   131072         // B * NPG
#define WIN    256            // lookback window
#define MAXN   16             // max neighbors kept
#define RAD2   49             // RADIUS_PX^2, RADIUS_PX = int(0.01*640+1) = 7
#define DTMAX  10000          // int(0.01 * 1e6)

__global__ __launch_bounds__(256)
void tgn_edges_kernel(const float* __restrict__ pos, int* __restrict__ out) {
    __shared__ int2 sp[512];            // packed (x | y<<16, t) for nodes [b0-256, b0+256)
    __shared__ int  ssrc[256 * MAXN];   // 16 KB: this block's src-slot tile

    const int tid = threadIdx.x;
    const int b0  = blockIdx.x * 256;
    const int i   = b0 + tid;

    // ---- Init the LDS output tile to -1 (LDS-only, no HBM traffic).
    {
        const int4 m1 = make_int4(-1, -1, -1, -1);
        int4* s4 = reinterpret_cast<int4*>(ssrc);
        #pragma unroll
        for (int k = 0; k < 4; ++k) s4[k * 256 + tid] = m1;
    }

    // ---- Stage + convert nodes [b0-256, b0+256) into LDS.
    #pragma unroll
    for (int s = 0; s < 2; ++s) {
        const int node = b0 - 256 + s * 256 + tid;
        int2 v = make_int2(0, 0);
        if (node >= 0) {
            const float x  = pos[3 * node + 0];
            const float y  = pos[3 * node + 1];
            const float tt = pos[3 * node + 2];
            // Must bit-match numpy float32: int32(denorm*pos + 0.001).
            // __fmul_rn/__fadd_rn prevent FMA contraction.
            const int px = (int)(__fadd_rn(__fmul_rn(640.0f,     x),  0.001f));
            const int py = (int)(__fadd_rn(__fmul_rn(480.0f,     y),  0.001f));
            const int pt = (int)(__fadd_rn(__fmul_rn(1000000.0f, tt), 0.001f));
            v.x = px | (py << 16);   // x in [0,640), y in [0,480) -> both fit 16 bits
            v.y = pt;
        }
        sp[s * 256 + tid] = v;
    }
    __syncthreads();

    const int2 pi = sp[256 + tid];
    const int  ix = pi.x & 0xffff;
    const int  iy = pi.x >> 16;
    const int  it = pi.y;

    int count = 0;
    int* __restrict__ myrow = ssrc + tid * MAXN;

    // A block needs the j>=0 / same-batch checks only if its window can
    // cross a batch boundary. b0 is a multiple of 256; batch boundaries are
    // multiples of 32768, so only (b0 & 32767)==0 blocks are "edge" blocks.
    const bool edge = (b0 & (NPG - 1)) == 0;

    if (!edge) {
        // Fast path: j>=0 and same-batch guaranteed; dt>=0 guaranteed
        // (t sorted ascending within batch; int conversion is monotonic).
        #pragma unroll 8
        for (int off = 1; off <= WIN; ++off) {
            const int2 pj = sp[256 + tid - off];
            const int dx = ix - (pj.x & 0xffff);
            const int dy = iy - (pj.x >> 16);
            const int d2 = dx * dx + dy * dy;
            const int dt = it - pj.y;
            const bool ok = (d2 <= RAD2) && (dt <= DTMAX);
            if (ok) {
                if (count < MAXN) myrow[count] = i - off;   // src = j
                ++count;
            }
        }
    } else {
        // Edge path: full condition set.
        #pragma unroll 4
        for (int off = 1; off <= WIN; ++off) {
            const int j = i - off;
            const int2 pj = sp[256 + tid - off];
            const int dx = ix - (pj.x & 0xffff);
            const int dy = iy - (pj.x >> 16);
            const int d2 = dx * dx + dy * dy;
            const int dt = it - pj.y;
            const bool ok = (j >= 0) && ((j >> 15) == (i >> 15)) &&
                            (d2 <= RAD2) && (dt >= 0) && (dt <= DTMAX);
            if (ok) {
                if (count < MAXN) myrow[count] = j;
                ++count;
            }
        }
    }

    __syncthreads();

    // ---- Stream the tile to global: fully contiguous int4 bursts.
    // src rows for this block occupy out[b0*16 .. b0*16+4096) exactly;
    // dst is derived: dst = (src >= 0) ? row : -1.
    const size_t srcbase = (size_t)b0 * MAXN;
    int4* __restrict__ gsrc = reinterpret_cast<int4*>(out + srcbase);
    int4* __restrict__ gdst = reinterpret_cast<int4*>(out + (size_t)NTOT * MAXN + srcbase);
    const int4* s4 = reinterpret_cast<const int4*>(ssrc);
    #pragma unroll
    for (int k = 0; k < 4; ++k) {
        const int idx4 = k * 256 + tid;
        const int4 v = s4[idx4];
        const int row = b0 + (idx4 >> 2);   // 4 consecutive ints share one output row
        int4 d;
        d.x = (v.x >= 0) ? row : -1;
        d.y = (v.y >= 0) ? row : -1;
        d.z = (v.z >= 0) ? row : -1;
        d.w = (v.w >= 0) ? row : -1;
        gsrc[idx4] = v;
        gdst[idx4] = d;
    }
}

extern "C" void kernel_launch(void* const* d_in, const int* in_sizes, int n_in,
                              void* d_out, int out_size, void* d_ws, size_t ws_size,
                              hipStream_t stream) {
    const float* pos = (const float*)d_in[0];
    int* out = (int*)d_out;
    tgn_edges_kernel<<<NTOT / 256, 256, 0, stream>>>(pos, out);
}

// Round 4
// 18.934 us; speedup vs baseline: 1.9203x; 1.6718x over previous
//
#include <hip/hip_runtime.h>

// Problem constants (fixed by setup_inputs / reference)
#define NPG    32768          // nodes per batch group
#define NTOT   131072         // B * NPG
#define MAXN   16             // max neighbors kept
#define RAD2   49             // RADIUS_PX^2, RADIUS_PX = int(0.01*640+1) = 7
#define DTMAX  10000          // int(0.01 * 1e6)
#define NPB    64             // nodes per block
#define QW     64             // offsets per quarter-window (256 = 4 x 64)

__global__ __launch_bounds__(256)
void tgn_edges_kernel(const float* __restrict__ pos, int* __restrict__ out) {
    __shared__ int2          sp[320];                // nodes [b0-256, b0+64), packed (x|y<<16, t)
    __shared__ unsigned char qslot[NPB][4][MAXN];    // per-(node,quarter) match list: stores off-1 (fits byte: max 255)
    __shared__ unsigned char scnt[NPB][4];           // per-(node,quarter) match count (capped at 16)
    __shared__ int           fin[NPB][MAXN];         // final src rows for this block

    const int tid = threadIdx.x;
    const int b0  = blockIdx.x * NPB;

    // ---- Stage + convert nodes [b0-256, b0+64) into LDS (320 nodes, 256 threads).
    #pragma unroll
    for (int s = 0; s < 2; ++s) {
        const int idx = s * 256 + tid;
        if (s == 0 || tid < NPB) {
            const int node = b0 - 256 + idx;
            int2 v = make_int2(0, 0);
            if (node >= 0) {
                const float x  = pos[3 * node + 0];
                const float y  = pos[3 * node + 1];
                const float tt = pos[3 * node + 2];
                // Must bit-match numpy float32: int32(denorm*pos + 0.001).
                // __fmul_rn/__fadd_rn prevent FMA contraction.
                const int px = (int)(__fadd_rn(__fmul_rn(640.0f,     x),  0.001f));
                const int py = (int)(__fadd_rn(__fmul_rn(480.0f,     y),  0.001f));
                const int pt = (int)(__fadd_rn(__fmul_rn(1000000.0f, tt), 0.001f));
                v.x = px | (py << 16);   // x in [0,640], y in [0,480] -> both fit 16 bits
                v.y = pt;
            }
            sp[idx] = v;
        }
    }
    __syncthreads();

    // ---- Pre-fill fin with -1 (LDS-only; merge later overwrites matched slots).
    reinterpret_cast<int4*>(&fin[0][0])[tid] = make_int4(-1, -1, -1, -1);  // 256 int4 = 4 KB

    // ---- Scan: thread (n, q) scans offsets [QW*q+1, QW*q+QW] for node b0+n.
    // Wave w == quarter w for nodes 0..63; lanes read consecutive sp entries.
    const int n = tid & (NPB - 1);
    const int q = tid >> 6;
    const int i = b0 + n;
    const int2 pi = sp[256 + n];
    const int ix = pi.x & 0xffff;
    const int iy = pi.x >> 16;
    const int it = pi.y;
    const int w0 = 256 + n - QW * q - 1;   // sp index for off = QW*q+1; decreases with s

    int cnt = 0;
    unsigned char* myq = &qslot[n][q][0];

    // A block needs j>=0 / same-batch / dt>=0 checks only when its 256-window
    // can cross a batch boundary: b0 mod 32768 in {0, 64, 128, 192}.
    const bool edgeb = (b0 & (NPG - 1)) < 256;

    if (!edgeb) {
        // Fast path: j>=0, same batch, dt>=0 all guaranteed (t sorted; int conv monotonic).
        #pragma unroll 8
        for (int s = 0; s < QW; ++s) {
            const int2 pj = sp[w0 - s];
            const int dx = ix - (pj.x & 0xffff);
            const int dy = iy - (pj.x >> 16);
            const int d2 = dx * dx + dy * dy;
            const int dt = it - pj.y;
            if ((d2 <= RAD2) && (dt <= DTMAX)) {
                if (cnt < MAXN) myq[cnt] = (unsigned char)(QW * q + s);  // = off-1
                ++cnt;
            }
        }
    } else {
        // Edge path: full condition set.
        #pragma unroll 4
        for (int s = 0; s < QW; ++s) {
            const int off = QW * q + 1 + s;
            const int j = i - off;
            const int2 pj = sp[w0 - s];
            const int dx = ix - (pj.x & 0xffff);
            const int dy = iy - (pj.x >> 16);
            const int d2 = dx * dx + dy * dy;
            const int dt = it - pj.y;
            if ((j >= 0) && ((j >> 15) == (i >> 15)) &&
                (d2 <= RAD2) && (dt >= 0) && (dt <= DTMAX)) {
                if (cnt < MAXN) myq[cnt] = (unsigned char)(QW * q + s);
                ++cnt;
            }
        }
    }
    scnt[n][q] = (unsigned char)(cnt < MAXN ? cnt : MAXN);
    __syncthreads();

    // ---- Merge: thread (n,q) copies its quarter's matches to fin[n] at the
    // prefix offset over lower quarters. Quarter lists are off-ordered and
    // concatenated in q order == global off order; k<16 cap == first-16 rule.
    {
        const uchar4 c4 = *reinterpret_cast<const uchar4*>(&scnt[n][0]);
        const int c0 = c4.x, c1 = c4.y, c2 = c4.z, c3 = c4.w;
        int start = 0;
        if (q > 0) start += c0;
        if (q > 1) start += c1;
        if (q > 2) start += c2;
        const int cq = (q == 0) ? c0 : (q == 1) ? c1 : (q == 2) ? c2 : c3;
        for (int e = 0; e < cq; ++e) {
            const int k = start + e;
            if (k < MAXN) fin[n][k] = i - 1 - (int)myq[e];   // j = i - off
        }
    }
    __syncthreads();

    // ---- Stream fin -> global: fully contiguous int4 bursts; dst derived.
    {
        const size_t base4 = (size_t)b0 * MAXN / 4;
        int4* __restrict__ gsrc = reinterpret_cast<int4*>(out) + base4;
        int4* __restrict__ gdst = reinterpret_cast<int4*>(out + (size_t)NTOT * MAXN) + base4;
        const int4 v = reinterpret_cast<const int4*>(&fin[0][0])[tid];
        const int row = b0 + (tid >> 2);   // 4 consecutive int4s per output row
        int4 d;
        d.x = (v.x >= 0) ? row : -1;
        d.y = (v.y >= 0) ? row : -1;
        d.z = (v.z >= 0) ? row : -1;
        d.w = (v.w >= 0) ? row : -1;
        gsrc[tid] = v;
        gdst[tid] = d;
    }
}

extern "C" void kernel_launch(void* const* d_in, const int* in_sizes, int n_in,
                              void* d_out, int out_size, void* d_ws, size_t ws_size,
                              hipStream_t stream) {
    const float* pos = (const float*)d_in[0];
    int* out = (int*)d_out;
    tgn_edges_kernel<<<NTOT / NPB, 256, 0, stream>>>(pos, out);
}

// Round 5
// 14.222 us; speedup vs baseline: 2.5565x; 1.3313x over previous
//
#include <hip/hip_runtime.h>

// Problem constants (fixed by setup_inputs / reference)
#define NPG    32768          // nodes per batch group
#define NTOT   131072         // B * NPG
#define MAXN   16             // max neighbors kept
#define RAD2   49             // RADIUS_PX^2, RADIUS_PX = int(0.01*640+1) = 7
#define DTMAX  10000u         // int(0.01 * 1e6)
#define NPB    64             // nodes per block
#define QW     64             // offsets per quarter-window (256 = 4 x 64)

__global__ __launch_bounds__(256, 8)
void tgn_edges_kernel(const float* __restrict__ pos, int* __restrict__ out) {
    __shared__ int           sp_xy[320];             // packed (x | y<<16) for nodes [b0-256, b0+64)
    __shared__ int           sp_t[320];              // t for same nodes
    __shared__ unsigned char qslot[NPB][4][MAXN];    // per-(node,quarter) matches: stores off-1
    __shared__ unsigned char scnt[NPB][4];           // per-(node,quarter) match count (capped 16)
    __shared__ int           fin[NPB][MAXN];         // final src rows for this block

    const int tid = threadIdx.x;
    const int b0  = blockIdx.x * NPB;

    // ---- Stage + convert nodes [b0-256, b0+64) into LDS (320 nodes, 256 threads).
    #pragma unroll
    for (int s = 0; s < 2; ++s) {
        const int idx = s * 256 + tid;
        if (s == 0 || tid < NPB) {
            const int node = b0 - 256 + idx;
            int vxy = 0, vt = 0;
            if (node >= 0) {
                const float x  = pos[3 * node + 0];
                const float y  = pos[3 * node + 1];
                const float tt = pos[3 * node + 2];
                // Must bit-match numpy float32: int32(denorm*pos + 0.001).
                // __fmul_rn/__fadd_rn prevent FMA contraction.
                const int px = (int)(__fadd_rn(__fmul_rn(640.0f,     x),  0.001f));
                const int py = (int)(__fadd_rn(__fmul_rn(480.0f,     y),  0.001f));
                const int pt = (int)(__fadd_rn(__fmul_rn(1000000.0f, tt), 0.001f));
                vxy = px | (py << 16);   // both fit 16 bits
                vt  = pt;
            }
            sp_xy[idx] = vxy;
            sp_t[idx]  = vt;
        }
    }

    // ---- Pre-fill fin with -1 (LDS-only; merge overwrites matched slots).
    reinterpret_cast<int4*>(&fin[0][0])[tid] = make_int4(-1, -1, -1, -1);
    __syncthreads();

    // ---- Scan: thread (n, q) scans offsets [QW*q+1, QW*q+QW] for node i = b0+n.
    const int n = tid & (NPB - 1);
    const int q = tid >> 6;
    const int i = b0 + n;
    const int pxy = sp_xy[256 + n];
    const int ix = pxy & 0xffff;
    const int iy = pxy >> 16;
    const int it = sp_t[256 + n];
    // Biased query: halves are (ix+8, iy+8). Prefilter: dx+8, dy+8 both in [0,15].
    const unsigned xyib = (unsigned)((ix + 8) | ((iy + 8) << 16));
    const int w0 = 255 + n - QW * q;     // sp index for off = QW*q+1 (s=0); idx = w0 - s

    // Fixed base so all 64 reads use compile-time immediate offsets (-> ds_read2_b32).
    const int* __restrict__ basep = &sp_xy[w0 - 63];   // index k <-> s = 63-k; k in [0,63]

    unsigned m0 = 0, m1 = 0;   // prefilter masks: m0 holds s=0..31 (bit 31-s), m1 s=32..63

    #pragma unroll 8
    for (int p = 0; p < 16; ++p) {
        const unsigned a = (unsigned)basep[63 - 2 * p];   // s = 2p
        const unsigned b = (unsigned)basep[62 - 2 * p];   // s = 2p+1
        unsigned t;
        // m = (m<<1)|bit(a); m = (m<<1)|bit(b)  via vcc shift-insert
        asm("v_pk_sub_i16 %0, %2, %3\n\t"
            "v_and_b32 %0, 0xfff0fff0, %0\n\t"
            "v_cmp_eq_u32 vcc, 0, %0\n\t"
            "v_addc_co_u32 %1, vcc, %1, %1, vcc\n\t"
            "v_pk_sub_i16 %0, %2, %4\n\t"
            "v_and_b32 %0, 0xfff0fff0, %0\n\t"
            "v_cmp_eq_u32 vcc, 0, %0\n\t"
            "v_addc_co_u32 %1, vcc, %1, %1, vcc"
            : "=&v"(t), "+v"(m0)
            : "v"(xyib), "v"(a), "v"(b)
            : "vcc");
    }
    #pragma unroll 8
    for (int p = 16; p < 32; ++p) {
        const unsigned a = (unsigned)basep[63 - 2 * p];
        const unsigned b = (unsigned)basep[62 - 2 * p];
        unsigned t;
        asm("v_pk_sub_i16 %0, %2, %3\n\t"
            "v_and_b32 %0, 0xfff0fff0, %0\n\t"
            "v_cmp_eq_u32 vcc, 0, %0\n\t"
            "v_addc_co_u32 %1, vcc, %1, %1, vcc\n\t"
            "v_pk_sub_i16 %0, %2, %4\n\t"
            "v_and_b32 %0, 0xfff0fff0, %0\n\t"
            "v_cmp_eq_u32 vcc, 0, %0\n\t"
            "v_addc_co_u32 %1, vcc, %1, %1, vcc"
            : "=&v"(t), "+v"(m1)
            : "v"(xyib), "v"(a), "v"(b)
            : "vcc");
    }

    // ---- Post-pass: exact check on the rare prefilter hits.
    // Edge blocks (window may cross batch boundary / j<0): b0 mod 32768 < 256.
    const bool edgeb = (b0 & (NPG - 1)) < 256;
    int cnt = 0;
    unsigned char* myq = &qslot[n][q][0];
    if (m0 | m1) {
        #pragma unroll
        for (int half = 0; half < 2; ++half) {
            unsigned m = half ? m1 : m0;
            const int sbase = half ? 32 : 0;
            while (m) {
                const int lz = __clz(m);
                m &= ~(0x80000000u >> lz);
                const int s = sbase + lz;
                const int idx = w0 - s;
                const int pj = sp_xy[idx];
                const int tj = sp_t[idx];
                const int dx = ix - (pj & 0xffff);
                const int dy = iy - (pj >> 16);
                const int d2 = dx * dx + dy * dy;
                const unsigned dt = (unsigned)(it - tj);  // dt>=0 auto (sorted, same batch)
                bool ok = (d2 <= RAD2) && (dt <= DTMAX);
                if (edgeb) {
                    const int j = i - (QW * q + 1 + s);
                    ok = ok && (j >= 0) && ((j >> 15) == (i >> 15));
                }
                if (ok) {
                    if (cnt < MAXN) myq[cnt] = (unsigned char)(QW * q + s);  // off-1
                    ++cnt;
                }
            }
        }
    }
    scnt[n][q] = (unsigned char)(cnt < MAXN ? cnt : MAXN);
    __syncthreads();

    // ---- Merge: thread (n,q) copies its quarter's matches into fin[n] at the
    // prefix offset over lower quarters (global first-16 rule preserved:
    // per-quarter counts are capped at 16, so later quarters start >=16 and drop).
    {
        const uchar4 c4 = *reinterpret_cast<const uchar4*>(&scnt[n][0]);
        const int c0 = c4.x, c1 = c4.y, c2 = c4.z, c3 = c4.w;
        int start = 0;
        if (q > 0) start += c0;
        if (q > 1) start += c1;
        if (q > 2) start += c2;
        const int cq = (q == 0) ? c0 : (q == 1) ? c1 : (q == 2) ? c2 : c3;
        for (int e = 0; e < cq; ++e) {
            const int k = start + e;
            if (k < MAXN) fin[n][k] = i - 1 - (int)myq[e];   // j = i - off
        }
    }
    __syncthreads();

    // ---- Stream fin -> global: fully contiguous int4 bursts; dst derived.
    {
        const size_t base4 = (size_t)b0 * MAXN / 4;
        int4* __restrict__ gsrc = reinterpret_cast<int4*>(out) + base4;
        int4* __restrict__ gdst = reinterpret_cast<int4*>(out + (size_t)NTOT * MAXN) + base4;
        const int4 v = reinterpret_cast<const int4*>(&fin[0][0])[tid];
        const int row = b0 + (tid >> 2);   // 4 consecutive int4s per output row
        int4 d;
        d.x = (v.x >= 0) ? row : -1;
        d.y = (v.y >= 0) ? row : -1;
        d.z = (v.z >= 0) ? row : -1;
        d.w = (v.w >= 0) ? row : -1;
        gsrc[tid] = v;
        gdst[tid] = d;
    }
}

extern "C" void kernel_launch(void* const* d_in, const int* in_sizes, int n_in,
                              void* d_out, int out_size, void* d_ws, size_t ws_size,
                              hipStream_t stream) {
    const float* pos = (const float*)d_in[0];
    int* out = (int*)d_out;
    tgn_edges_kernel<<<NTOT / NPB, 256, 0, stream>>>(pos, out);
}